// Round 4
// baseline (219.843 us; speedup 1.0000x reference)
//
#include <hip/hip_runtime.h>
#include <math.h>

// Problem constants (fixed by the reference).
constexpr int Ac = 16;    // actions
constexpr int Bc = 32;    // batch
constexpr int Lc = 1024;  // sequence
constexpr int Xc = 1024;  // x feature
constexpr int Yc = 1024;  // y feature
constexpr int Cc = Ac + Bc;  // 48 combined coefficient rows

// Native clang vector type — __builtin_nontemporal_load requires this.
typedef float vfloat4 __attribute__((ext_vector_type(4)));

// ---------------------------------------------------------------------------
// Wave/block reduction helpers (wave = 64 lanes on CDNA)
// ---------------------------------------------------------------------------
__device__ __forceinline__ float waveReduceSum(float v) {
#pragma unroll
    for (int off = 32; off > 0; off >>= 1) v += __shfl_down(v, off, 64);
    return v;
}

__device__ __forceinline__ float waveReduceMax(float v) {
#pragma unroll
    for (int off = 32; off > 0; off >>= 1) v = fmaxf(v, __shfl_down(v, off, 64));
    return v;
}

// ---------------------------------------------------------------------------
// k1: O[48,X] = C[48,Y] @ W[Y,X]; C rows 0..15 = wa_h, rows 16..47 = y.
// O rows 0..15 -> s_raw (pre-softmax scores), rows 16..47 -> yW.
// EXACT R2/round-0 measured-best version: grid (X/256=4, Y/32=32) = 128
// blocks, [48x32] coef chunk in LDS, 32 weight values per thread, 1536 FMAs,
// 48 atomicAdds. (R7's 256-block/16-chunk variant was part of a confounded
// +2us regression — reverted. R5 lesson: NO fences; kernel boundary is the
// free coherence point.)
// ---------------------------------------------------------------------------
__global__ __launch_bounds__(256) void k1_proj(
        const float* __restrict__ weight, const float* __restrict__ yv,
        const float* __restrict__ wa_h, float* __restrict__ s_raw,
        float* __restrict__ yW) {
    const int x  = blockIdx.x * 256 + threadIdx.x;
    const int y0 = blockIdx.y * 32;

    __shared__ float cLDS[Cc][32];  // 6 KiB

    // Cooperative coef load: 1536 elements, 6 per thread (coalesced).
#pragma unroll
    for (int k = 0; k < 6; ++k) {
        const int idx = threadIdx.x + k * 256;
        const int row = idx >> 5;
        const int col = idx & 31;
        cLDS[row][col] = (row < Ac) ? wa_h[row * Yc + y0 + col]
                                    : yv[(row - Ac) * Yc + y0 + col];
    }

    // Prefetch this thread's 32 weight values (independent, coalesced).
    float w[32];
#pragma unroll
    for (int t = 0; t < 32; ++t) w[t] = weight[(size_t)(y0 + t) * Xc + x];

    __syncthreads();

    float acc[Cc];
#pragma unroll
    for (int j = 0; j < Cc; ++j) acc[j] = 0.0f;

    const float4* cvec = (const float4*)cLDS;
#pragma unroll
    for (int j = 0; j < Cc; ++j) {
#pragma unroll
        for (int q = 0; q < 8; ++q) {
            const float4 c = cvec[j * 8 + q];  // LDS b128 broadcast (free)
            acc[j] = fmaf(w[q * 4 + 0], c.x, acc[j]);
            acc[j] = fmaf(w[q * 4 + 1], c.y, acc[j]);
            acc[j] = fmaf(w[q * 4 + 2], c.z, acc[j]);
            acc[j] = fmaf(w[q * 4 + 3], c.w, acc[j]);
        }
    }

#pragma unroll
    for (int j = 0; j < Ac; ++j) atomicAdd(&s_raw[j * Xc + x], acc[j]);
#pragma unroll
    for (int j = Ac; j < Cc; ++j) atomicAdd(&yW[(j - Ac) * Xc + x], acc[j]);
}

// ---------------------------------------------------------------------------
// k3: xWy[b,l] = sum_x x[b,l,x] * Wy[b,x].
// R2-proven shape: grid (L/16=64, B) = 2048 blocks (exactly the 8-blk/CU
// residency limit), 4 waves, 4 rows per wave interleaved.
// R8 change (ONLY delta vs R2): prologue latency hiding. The softmax
// prologue's serial chain (actions -> s_raw -> 2 reduces -> yW/bias -> Wy)
// ran BEFORE any x load was issued, adding startup latency on the critical
// path of all 2048 co-resident blocks. Now: issue the first 8 x b128 loads +
// yW + bias at kernel entry; the softmax computes while those drain; after
// the Wy barrier, issue the back-half loads before consuming the front half.
// ---------------------------------------------------------------------------
__global__ __launch_bounds__(256) void k3_dot(
        const float* __restrict__ x, const float* __restrict__ yW,
        const float* __restrict__ s_raw, const float* __restrict__ bias,
        const int* __restrict__ actions, float* __restrict__ xWy) {
    const int b    = blockIdx.y;
    const int l0   = blockIdx.x * 16;
    const int tid  = threadIdx.x;
    const int wave = tid >> 6;
    const int lane = tid & 63;
    __shared__ float Wy[Xc];
    __shared__ float smax[4];
    __shared__ float ssum[4];

    // ---- entry: issue every prologue-independent load first ----
    const int act = actions[b];  // uniform s_load; s_raw addrs depend on it

    const float* xb = x + ((size_t)b * Lc + l0) * Xc;
    vfloat4 pre[2][4];  // first 2 of 4 k-iters, 4 rows each (8 x b128)
#pragma unroll
    for (int k = 0; k < 2; ++k) {
        const int idx = lane + k * 64;
#pragma unroll
        for (int rr = 0; rr < 4; ++rr) {
            const int l = wave + rr * 4;
            pre[k][rr] = __builtin_nontemporal_load(
                (const vfloat4*)(xb + (size_t)l * Xc) + idx);
        }
    }
    float yWv[4], bv[4];
#pragma unroll
    for (int k = 0; k < 4; ++k) {
        yWv[k] = yW[b * Xc + tid + k * 256];
        bv[k]  = bias[tid + k * 256];
    }

    // ---- fused k2: softmax of s_raw[act,:] (overlaps in-flight loads) ----
    float sv[4];
    float mx = -INFINITY;
#pragma unroll
    for (int k = 0; k < 4; ++k) {
        sv[k] = s_raw[act * Xc + tid + k * 256];
        mx = fmaxf(mx, sv[k]);
    }
    mx = waveReduceMax(mx);
    if (lane == 0) smax[wave] = mx;
    __syncthreads();
    mx = fmaxf(fmaxf(smax[0], smax[1]), fmaxf(smax[2], smax[3]));

    float sum = 0.0f;
#pragma unroll
    for (int k = 0; k < 4; ++k) {
        sv[k] = __expf(sv[k] - mx);
        sum += sv[k];
    }
    sum = waveReduceSum(sum);
    if (lane == 0) ssum[wave] = sum;
    __syncthreads();
    sum = ssum[0] + ssum[1] + ssum[2] + ssum[3];
    const float inv = 1.0f / sum;

    // ---- build Wy in LDS (pure VALU now — inputs already in regs) ----
#pragma unroll
    for (int k = 0; k < 4; ++k) {
        const int xi = tid + k * 256;
        Wy[xi] = fmaf(yWv[k], sv[k] * inv, bv[k]);
    }
    __syncthreads();

    // ---- dot: issue back-half loads, then consume front half ----
    const float4* WyV = (const float4*)Wy;

    vfloat4 post[2][4];
#pragma unroll
    for (int k = 0; k < 2; ++k) {
        const int idx = lane + (k + 2) * 64;
#pragma unroll
        for (int rr = 0; rr < 4; ++rr) {
            const int l = wave + rr * 4;
            post[k][rr] = __builtin_nontemporal_load(
                (const vfloat4*)(xb + (size_t)l * Xc) + idx);
        }
    }

    float acc[4] = {0.0f, 0.0f, 0.0f, 0.0f};
#pragma unroll
    for (int k = 0; k < 2; ++k) {
        const float4 wv = WyV[lane + k * 64];
#pragma unroll
        for (int rr = 0; rr < 4; ++rr) {
            acc[rr] = fmaf(pre[k][rr].x, wv.x, acc[rr]);
            acc[rr] = fmaf(pre[k][rr].y, wv.y, acc[rr]);
            acc[rr] = fmaf(pre[k][rr].z, wv.z, acc[rr]);
            acc[rr] = fmaf(pre[k][rr].w, wv.w, acc[rr]);
        }
    }
#pragma unroll
    for (int k = 0; k < 2; ++k) {
        const float4 wv = WyV[lane + (k + 2) * 64];
#pragma unroll
        for (int rr = 0; rr < 4; ++rr) {
            acc[rr] = fmaf(post[k][rr].x, wv.x, acc[rr]);
            acc[rr] = fmaf(post[k][rr].y, wv.y, acc[rr]);
            acc[rr] = fmaf(post[k][rr].z, wv.z, acc[rr]);
            acc[rr] = fmaf(post[k][rr].w, wv.w, acc[rr]);
        }
    }

#pragma unroll
    for (int rr = 0; rr < 4; ++rr) {
        const float a = waveReduceSum(acc[rr]);
        if (lane == 0) xWy[b * Lc + l0 + wave + rr * 4] = a;
    }
}

// ---------------------------------------------------------------------------
// k4: out[b,:] = log_softmax_L(where(mask, -inf, xWy[b,:])). grid: B blocks.
// (Exact round-0 version.)
// ---------------------------------------------------------------------------
__global__ __launch_bounds__(256) void k4_logsoftmax(
        const float* __restrict__ xWy, const unsigned char* __restrict__ mask,
        float* __restrict__ out) {
    const int b    = blockIdx.x;
    const int tid  = threadIdx.x;
    const int wave = tid >> 6;
    const int lane = tid & 63;
    __shared__ float smax[4];
    __shared__ float ssum[4];

    float v[4];
    float mx = -INFINITY;
#pragma unroll
    for (int k = 0; k < 4; ++k) {
        const int l = tid + k * 256;
        float t = xWy[b * Lc + l];
        if (mask[b * Lc + l]) t = -INFINITY;
        v[k] = t;
        mx = fmaxf(mx, t);
    }
    mx = waveReduceMax(mx);
    if (lane == 0) smax[wave] = mx;
    __syncthreads();
    mx = fmaxf(fmaxf(smax[0], smax[1]), fmaxf(smax[2], smax[3]));

    float sum = 0.0f;
#pragma unroll
    for (int k = 0; k < 4; ++k) sum += __expf(v[k] - mx);
    sum = waveReduceSum(sum);
    if (lane == 0) ssum[wave] = sum;
    __syncthreads();
    sum = ssum[0] + ssum[1] + ssum[2] + ssum[3];

    const float lse = mx + __logf(sum);
#pragma unroll
    for (int k = 0; k < 4; ++k) out[b * Lc + tid + k * 256] = v[k] - lse;
}

// ---------------------------------------------------------------------------
// Launch. Inputs (setup_inputs order):
//   0 x      [B,L,X] f32      1 y      [B,Y] f32     2 x_mask [B,L] bool
//   3 actions[B] int32        4 weight [Y,X] f32     5 bias   [X] f32
//   6 wa_h   [A,Y,1] f32
// Output: [B,L] f32 log-softmax.
// Workspace layout:
//   [0,64K)     s_raw   A*X f32   (atomic-accumulated, zeroed below)
//   [64K,192K)  yW      B*X f32   (atomic-accumulated, zeroed below)
//   [192K,320K) xWy     B*L f32
// ---------------------------------------------------------------------------
extern "C" void kernel_launch(void* const* d_in, const int* in_sizes, int n_in,
                              void* d_out, int out_size, void* d_ws, size_t ws_size,
                              hipStream_t stream) {
    const float* x          = (const float*)d_in[0];
    const float* yv         = (const float*)d_in[1];
    const unsigned char* xm = (const unsigned char*)d_in[2];
    const int* actions      = (const int*)d_in[3];
    const float* weight     = (const float*)d_in[4];
    const float* bias       = (const float*)d_in[5];
    const float* wa_h       = (const float*)d_in[6];
    float* out              = (float*)d_out;

    char* ws      = (char*)d_ws;
    float* s_raw  = (float*)(ws);
    float* yW     = (float*)(ws + 64 * 1024);
    float* xWy    = (float*)(ws + 192 * 1024);

    // Zero only the atomic accumulation buffers (192 KiB).
    (void)hipMemsetAsync(d_ws, 0, 192 * 1024, stream);

    k1_proj<<<dim3(Xc / 256, Yc / 32), 256, 0, stream>>>(weight, yv, wa_h, s_raw, yW);
    k3_dot<<<dim3(Lc / 16, Bc), 256, 0, stream>>>(x, yW, s_raw, bias, actions, xWy);
    k4_logsoftmax<<<Bc, 256, 0, stream>>>(xWy, xm, out);
}

// Round 5
// 212.127 us; speedup vs baseline: 1.0364x; 1.0364x over previous
//
#include <hip/hip_runtime.h>
#include <math.h>

// Problem constants (fixed by the reference).
constexpr int Ac = 16;    // actions
constexpr int Bc = 32;    // batch
constexpr int Lc = 1024;  // sequence
constexpr int Xc = 1024;  // x feature
constexpr int Yc = 1024;  // y feature
constexpr int Cc = Ac + Bc;  // 48 combined coefficient rows

// Native clang vector type — __builtin_nontemporal_load requires this.
typedef float vfloat4 __attribute__((ext_vector_type(4)));

// ---------------------------------------------------------------------------
// Wave/block reduction helpers (wave = 64 lanes on CDNA)
// ---------------------------------------------------------------------------
__device__ __forceinline__ float waveReduceSum(float v) {
#pragma unroll
    for (int off = 32; off > 0; off >>= 1) v += __shfl_down(v, off, 64);
    return v;
}

__device__ __forceinline__ float waveReduceMax(float v) {
#pragma unroll
    for (int off = 32; off > 0; off >>= 1) v = fmaxf(v, __shfl_down(v, off, 64));
    return v;
}

// ---------------------------------------------------------------------------
// k1: O[48,X] = C[48,Y] @ W[Y,X]; C rows 0..15 = wa_h, rows 16..47 = y.
// O rows 0..15 -> s_raw (pre-softmax scores), rows 16..47 -> yW.
// EXACT R2/round-0 measured-best version: grid (X/256=4, Y/32=32) = 128
// blocks, [48x32] coef chunk in LDS, 32 weight values per thread, 1536 FMAs,
// 48 atomicAdds. NO fences — kernel boundary is the free coherence point
// (R5 lesson: agent-scope release = buffer_wbl2 per block, disaster).
// ---------------------------------------------------------------------------
__global__ __launch_bounds__(256) void k1_proj(
        const float* __restrict__ weight, const float* __restrict__ yv,
        const float* __restrict__ wa_h, float* __restrict__ s_raw,
        float* __restrict__ yW) {
    const int x  = blockIdx.x * 256 + threadIdx.x;
    const int y0 = blockIdx.y * 32;

    __shared__ float cLDS[Cc][32];  // 6 KiB

    // Cooperative coef load: 1536 elements, 6 per thread (coalesced).
#pragma unroll
    for (int k = 0; k < 6; ++k) {
        const int idx = threadIdx.x + k * 256;
        const int row = idx >> 5;
        const int col = idx & 31;
        cLDS[row][col] = (row < Ac) ? wa_h[row * Yc + y0 + col]
                                    : yv[(row - Ac) * Yc + y0 + col];
    }

    // Prefetch this thread's 32 weight values (independent, coalesced).
    float w[32];
#pragma unroll
    for (int t = 0; t < 32; ++t) w[t] = weight[(size_t)(y0 + t) * Xc + x];

    __syncthreads();

    float acc[Cc];
#pragma unroll
    for (int j = 0; j < Cc; ++j) acc[j] = 0.0f;

    const float4* cvec = (const float4*)cLDS;
#pragma unroll
    for (int j = 0; j < Cc; ++j) {
#pragma unroll
        for (int q = 0; q < 8; ++q) {
            const float4 c = cvec[j * 8 + q];  // LDS b128 broadcast (free)
            acc[j] = fmaf(w[q * 4 + 0], c.x, acc[j]);
            acc[j] = fmaf(w[q * 4 + 1], c.y, acc[j]);
            acc[j] = fmaf(w[q * 4 + 2], c.z, acc[j]);
            acc[j] = fmaf(w[q * 4 + 3], c.w, acc[j]);
        }
    }

#pragma unroll
    for (int j = 0; j < Ac; ++j) atomicAdd(&s_raw[j * Xc + x], acc[j]);
#pragma unroll
    for (int j = Ac; j < Cc; ++j) atomicAdd(&yW[(j - Ac) * Xc + x], acc[j]);
}

// ---------------------------------------------------------------------------
// k2_wy: per-batch Wy materialization (R9). One block per b:
//   p = softmax_x(s_raw[actions[b],:]);  Wy[b,:] = yW[b,:]*p + bias.
// This removes the softmax/Wy prologue (12KB L2 reads + 2 reduce trees +
// 3 barriers) from all 2048 k3 blocks; k3 becomes a pure stream kernel.
// Cost: one extra ~1.5us dispatch + 128KB write (L2-hot for k3).
// (R8 lesson: hoisting loads ACROSS the prologue blew VGPR/occupancy;
// deleting the dependency is free.)
// ---------------------------------------------------------------------------
__global__ __launch_bounds__(256) void k2_wy(
        const float* __restrict__ s_raw, const float* __restrict__ yW,
        const float* __restrict__ bias, const int* __restrict__ actions,
        float* __restrict__ Wy) {
    const int b    = blockIdx.x;
    const int tid  = threadIdx.x;
    const int wave = tid >> 6;
    const int lane = tid & 63;
    __shared__ float smax[4];
    __shared__ float ssum[4];

    const int act = actions[b];

    float sv[4];
    float mx = -INFINITY;
#pragma unroll
    for (int k = 0; k < 4; ++k) {
        sv[k] = s_raw[act * Xc + tid + k * 256];
        mx = fmaxf(mx, sv[k]);
    }
    mx = waveReduceMax(mx);
    if (lane == 0) smax[wave] = mx;
    __syncthreads();
    mx = fmaxf(fmaxf(smax[0], smax[1]), fmaxf(smax[2], smax[3]));

    float sum = 0.0f;
#pragma unroll
    for (int k = 0; k < 4; ++k) {
        sv[k] = __expf(sv[k] - mx);
        sum += sv[k];
    }
    sum = waveReduceSum(sum);
    if (lane == 0) ssum[wave] = sum;
    __syncthreads();
    sum = ssum[0] + ssum[1] + ssum[2] + ssum[3];
    const float inv = 1.0f / sum;

#pragma unroll
    for (int k = 0; k < 4; ++k) {
        const int xi = tid + k * 256;
        Wy[b * Xc + xi] = fmaf(yW[b * Xc + xi], sv[k] * inv, bias[xi]);
    }
}

// ---------------------------------------------------------------------------
// k3: xWy[b,l] = sum_x x[b,l,x] * Wy[b,x] — pure streaming dot (R9).
// Wy comes precomputed from k2_wy: each lane needs only WyV[lane + k*64]
// for k=0..3 (identical for all rows, since the row-reduce is a wave
// shuffle) -> 4 float4 global loads (L2-hot), NO LDS, NO barriers, NO
// reductions before the x-stream starts. Inner loop is the R2-measured-best
// 4-rows-interleaved batched-b128 pattern, unchanged.
// grid (L/16=64, B) = 2048 blocks (= the 8-blk/CU residency limit), 4 waves.
// ---------------------------------------------------------------------------
__global__ __launch_bounds__(256) void k3_dot(
        const float* __restrict__ x, const float* __restrict__ Wy,
        float* __restrict__ xWy) {
    const int b    = blockIdx.y;
    const int l0   = blockIdx.x * 16;
    const int wave = threadIdx.x >> 6;
    const int lane = threadIdx.x & 63;

    // 16 floats of Wy per lane — covers the whole row across the wave.
    const float4* WyV = (const float4*)(Wy + b * Xc);
    float4 wv[4];
#pragma unroll
    for (int k = 0; k < 4; ++k) wv[k] = WyV[lane + k * 64];

    const float* xb = x + ((size_t)b * Lc + l0) * Xc;

    float acc[4] = {0.0f, 0.0f, 0.0f, 0.0f};
#pragma unroll
    for (int k = 0; k < 4; ++k) {
        const int idx = lane + k * 64;
        vfloat4 xv[4];
#pragma unroll
        for (int rr = 0; rr < 4; ++rr) {
            const int l = wave + rr * 4;
            xv[rr] = __builtin_nontemporal_load(
                (const vfloat4*)(xb + (size_t)l * Xc) + idx);
        }
#pragma unroll
        for (int rr = 0; rr < 4; ++rr) {
            acc[rr] = fmaf(xv[rr].x, wv[k].x, acc[rr]);
            acc[rr] = fmaf(xv[rr].y, wv[k].y, acc[rr]);
            acc[rr] = fmaf(xv[rr].z, wv[k].z, acc[rr]);
            acc[rr] = fmaf(xv[rr].w, wv[k].w, acc[rr]);
        }
    }

#pragma unroll
    for (int rr = 0; rr < 4; ++rr) {
        const float a = waveReduceSum(acc[rr]);
        if (lane == 0) xWy[b * Lc + l0 + wave + rr * 4] = a;
    }
}

// ---------------------------------------------------------------------------
// k4: out[b,:] = log_softmax_L(where(mask, -inf, xWy[b,:])). grid: B blocks.
// (Exact round-0 version.)
// ---------------------------------------------------------------------------
__global__ __launch_bounds__(256) void k4_logsoftmax(
        const float* __restrict__ xWy, const unsigned char* __restrict__ mask,
        float* __restrict__ out) {
    const int b    = blockIdx.x;
    const int tid  = threadIdx.x;
    const int wave = tid >> 6;
    const int lane = tid & 63;
    __shared__ float smax[4];
    __shared__ float ssum[4];

    float v[4];
    float mx = -INFINITY;
#pragma unroll
    for (int k = 0; k < 4; ++k) {
        const int l = tid + k * 256;
        float t = xWy[b * Lc + l];
        if (mask[b * Lc + l]) t = -INFINITY;
        v[k] = t;
        mx = fmaxf(mx, t);
    }
    mx = waveReduceMax(mx);
    if (lane == 0) smax[wave] = mx;
    __syncthreads();
    mx = fmaxf(fmaxf(smax[0], smax[1]), fmaxf(smax[2], smax[3]));

    float sum = 0.0f;
#pragma unroll
    for (int k = 0; k < 4; ++k) sum += __expf(v[k] - mx);
    sum = waveReduceSum(sum);
    if (lane == 0) ssum[wave] = sum;
    __syncthreads();
    sum = ssum[0] + ssum[1] + ssum[2] + ssum[3];

    const float lse = mx + __logf(sum);
#pragma unroll
    for (int k = 0; k < 4; ++k) out[b * Lc + tid + k * 256] = v[k] - lse;
}

// ---------------------------------------------------------------------------
// Launch. Inputs (setup_inputs order):
//   0 x      [B,L,X] f32      1 y      [B,Y] f32     2 x_mask [B,L] bool
//   3 actions[B] int32        4 weight [Y,X] f32     5 bias   [X] f32
//   6 wa_h   [A,Y,1] f32
// Output: [B,L] f32 log-softmax.
// Workspace layout:
//   [0,64K)     s_raw   A*X f32   (atomic-accumulated, zeroed below)
//   [64K,192K)  yW      B*X f32   (atomic-accumulated, zeroed below)
//   [192K,320K) xWy     B*L f32
//   [320K,448K) Wy      B*X f32   (k2_wy output)
// ---------------------------------------------------------------------------
extern "C" void kernel_launch(void* const* d_in, const int* in_sizes, int n_in,
                              void* d_out, int out_size, void* d_ws, size_t ws_size,
                              hipStream_t stream) {
    const float* x          = (const float*)d_in[0];
    const float* yv         = (const float*)d_in[1];
    const unsigned char* xm = (const unsigned char*)d_in[2];
    const int* actions      = (const int*)d_in[3];
    const float* weight     = (const float*)d_in[4];
    const float* bias       = (const float*)d_in[5];
    const float* wa_h       = (const float*)d_in[6];
    float* out              = (float*)d_out;

    char* ws      = (char*)d_ws;
    float* s_raw  = (float*)(ws);
    float* yW     = (float*)(ws + 64 * 1024);
    float* xWy    = (float*)(ws + 192 * 1024);
    float* Wy     = (float*)(ws + 320 * 1024);

    // Zero only the atomic accumulation buffers (192 KiB).
    (void)hipMemsetAsync(d_ws, 0, 192 * 1024, stream);

    k1_proj<<<dim3(Xc / 256, Yc / 32), 256, 0, stream>>>(weight, yv, wa_h, s_raw, yW);
    k2_wy<<<Bc, 256, 0, stream>>>(s_raw, yW, bias, actions, Wy);
    k3_dot<<<dim3(Lc / 16, Bc), 256, 0, stream>>>(x, Wy, xWy);
    k4_logsoftmax<<<Bc, 256, 0, stream>>>(xWy, xm, out);
}